// Round 13
// baseline (242.413 us; speedup 1.0000x reference)
//
#include <hip/hip_runtime.h>
#include <hip/hip_bf16.h>
#include <stdint.h>

#define T_DIM 2048
#define N_DIM 512
#define DV_DIM 128
#define NH 16          // B*H

typedef __bf16 bf16x8 __attribute__((ext_vector_type(8)));
typedef float f32x4 __attribute__((ext_vector_type(4)));
typedef float f32x2 __attribute__((ext_vector_type(2)));
typedef unsigned int u32x2 __attribute__((ext_vector_type(2)));
typedef unsigned int u32x4 __attribute__((ext_vector_type(4)));

__device__ __forceinline__ unsigned bf16rne(float x) {
  unsigned u = __builtin_bit_cast(unsigned, x);
  return (u + 0x7FFFu + ((u >> 16) & 1u)) >> 16;
}

__device__ __forceinline__ void load_lds16(const void* g, void* l) {
  __builtin_amdgcn_global_load_lds((const __attribute__((address_space(1))) void*)g,
                                   (__attribute__((address_space(3))) void*)l, 16, 0, 0);
}

// ---------------- RoPE: Q fp32 -> QR bf16  [bh][t][n] ----------------
__global__ void rope_kernel(const float* __restrict__ Q, const float* __restrict__ freqs,
                            unsigned int* __restrict__ qrOut) {
  const int total = NH * T_DIM * (N_DIM / 2);  // pairs
  for (int p = blockIdx.x * blockDim.x + threadIdx.x; p < total;
       p += gridDim.x * blockDim.x) {
    int n2 = p & 255;            // N/2 = 256
    int t = (p >> 8) & 2047;
    float f = freqs[2 * n2];
    f32x2 q = *(const f32x2*)(Q + 2 * (size_t)p);
    float ph = (float)t * f;
    ph = ph - floorf(ph);                 // revolutions in [0,1)
    float sn = __builtin_amdgcn_sinf(ph);
    float cn = __builtin_amdgcn_cosf(ph);
    float o0 = q.x * cn - q.y * sn;
    float o1 = q.y * cn + q.x * sn;
    qrOut[p] = bf16rne(o0) | (bf16rne(o1) << 16);
  }
}

// ---- V fp32 [bh][t][d] -> frag-linear bf16 blocks (16x16x32 B-frag):
// vt32[bh][sblk32][slot j=df*64+lane][i=0..7] = V[s0+8*lg+i][16*df+lh]
__global__ void vtrans_kernel(const float* __restrict__ V, unsigned short* __restrict__ vt32) {
  __shared__ unsigned short tile[32][128];
  const int blk = blockIdx.x;
  const int bh = blk >> 6;
  const int sb = blk & 63;
  const float* src = V + ((size_t)bh * T_DIM + sb * 32) * DV_DIM;
  const int tid = threadIdx.x;
#pragma unroll
  for (int i = 0; i < 16; ++i) {
    int idx = i * 256 + tid;          // 0..4095 over [32][128]
    tile[idx >> 7][idx & 127] = (unsigned short)bf16rne(src[idx]);
  }
  __syncthreads();
  unsigned short* dst = vt32 + (size_t)blk * 4096;
#pragma unroll
  for (int jj = 0; jj < 2; ++jj) {
    int j = jj * 256 + tid;           // slot 0..511
    int df = j >> 6, ln = j & 63;
    int lh2 = ln & 15, lg2 = ln >> 4;
    unsigned short tmp[8];
#pragma unroll
    for (int i = 0; i < 8; ++i) tmp[i] = tile[8 * lg2 + i][16 * df + lh2];
    *(u32x4*)(dst + j * 8) = *(u32x4*)tmp;
  }
}

// ---------------- fused masked attention ----------------
// 1024 wgs x 256 thr (4 waves), __launch_bounds__(256,4) -> target 4 wgs/CU,
// 16 waves/CU = 4/SIMD. wg = (head pinned to XCD, slot j 0..15, kchunk c).
// HALF-BLOCK pairing: block b has 4(b+1) causal s-steps, split into halves
// of 2(b+1); wg j runs (block j, sblk 0..2j+1) then (block 15-j, sblk
// 32-2j..63-4j) -> uniform 34 steps. Inner step = v10's proven body. Q via
// NORMAL compiler-tracked loads at prologue/seam (v5/v6-proven; no untracked
// asm loads anywhere). Counted s_waitcnt vmcnt(4) staging pipeline;
// frag-linear conflict-free LDS; fp32 atomicAdd partials.
__global__ __launch_bounds__(256, 4)
void attn_kernel(const unsigned short* __restrict__ qr,
                 const unsigned short* __restrict__ vt32,
                 float* __restrict__ out) {
  __shared__ unsigned short k_lds[2][4096];  // [buf][frag f=st*4+ks][lane*8]
  __shared__ unsigned short v_lds[2][4096];  // [buf][frag df][lane*8]
  __shared__ unsigned short s_lds[8 * 512];  // [w*2+m][A-frag-linear 512]

  const int tid = threadIdx.x;
  const int w = tid >> 6;
  const int lane = tid & 63;
  const int lh = lane & 15;
  const int lg = lane >> 4;

  const int bid = blockIdx.x;
  const int u = bid >> 3;
  const int head = (bid & 7) + 8 * (u & 1);   // 2 heads per XCD
  const int rest = u >> 1;                    // 0..63
  const int c = rest & 3;                     // kchunk
  const int j = ((rest >> 2) + 4 * c) & 15;   // slot, staggered per kchunk
  const int b0 = j, b1 = 15 - j;              // 128-row blocks
  const int n0 = 2 * j + 2;                   // seg0 steps; total 34
  const int s1off = 30 - 4 * j;               // seg1: sblk = s1off + t

  const unsigned short* qr_h = qr + (size_t)head * (T_DIM * N_DIM);
  const unsigned short* vt_h = vt32 + (size_t)head * (64 * 4096);
  float* const out_h = out + (size_t)head * T_DIM * DV_DIM;

  // staging source offsets (bytes): 2 K slots/thread, frag-linear dest
  int koff[2];
#pragma unroll
  for (int it = 0; it < 2; ++it) {
    int slot = it * 256 + tid;           // 0..511
    int f = slot >> 6, l = slot & 63;
    int st = f >> 2, ks = f & 3;
    koff[it] = (st * 16 + (l & 15)) * 1024 + c * 256 + ks * 64 + (l >> 4) * 16;
  }

  u32x4 q0[2][4];
  auto qload = [&](int b) {   // normal compiler-tracked loads (v5/v6-proven)
    const unsigned short* pa = qr_h + (size_t)(b * 128 + 32 * w + lh) * N_DIM + c * 128 + lg * 8;
    const unsigned short* pb = pa + 16 * N_DIM;
#pragma unroll
    for (int ks = 0; ks < 4; ++ks) {
      q0[0][ks] = *(const u32x4*)(pa + ks * 32);
      q0[1][ks] = *(const u32x4*)(pb + ks * 32);
    }
  };

  const f32x4 fzero = {0.f, 0.f, 0.f, 0.f};
  f32x4 o[2][8];
#pragma unroll
  for (int m = 0; m < 2; ++m)
#pragma unroll
    for (int d = 0; d < 8; ++d) o[m][d] = fzero;

  auto flushO = [&](int b) {
    const int tb2 = b * 128 + 32 * w;
#pragma unroll
    for (int m = 0; m < 2; ++m)
#pragma unroll
      for (int df = 0; df < 8; ++df)
#pragma unroll
        for (int r = 0; r < 4; ++r)
          atomicAdd(out_h + (size_t)(tb2 + 16 * m + 4 * lg + r) * DV_DIM + df * 16 + lh,
                    o[m][df][r]);
  };
  // 4 global_load_lds per thread per stage -> vmcnt unit = 4
  auto stage = [&](int sblk, int buf) {
    const char* kb = (const char*)qr_h + (size_t)sblk * 32768;
#pragma unroll
    for (int it = 0; it < 2; ++it)
      load_lds16(kb + koff[it], (char*)&k_lds[buf][0] + (it * 256 + tid) * 16);
    const char* vb = (const char*)vt_h + (size_t)sblk * 8192;
#pragma unroll
    for (int it = 0; it < 2; ++it)
      load_lds16(vb + (it * 256 + tid) * 16, (char*)&v_lds[buf][0] + (it * 256 + tid) * 16);
  };

  qload(b0);
  stage(0, 0);
  asm volatile("s_waitcnt vmcnt(0)" ::: "memory");  // stage0 landed

  for (int t = 0; t < 34; ++t) {
    if (t == n0) {    // segment seam: emit block b0, load seg-1 Q
      flushO(b0);
      qload(b1);
#pragma unroll
      for (int m = 0; m < 2; ++m)
#pragma unroll
        for (int d = 0; d < 8; ++d) o[m][d] = fzero;
    }
    const int buf = t & 1;
    if (t + 1 < 34) {
      const int tn = t + 1;
      stage((tn < n0) ? tn : (s1off + tn), buf ^ 1);
      asm volatile("s_waitcnt vmcnt(4)" ::: "memory");   // stage(t) landed
    } else {
      asm volatile("s_waitcnt vmcnt(0)" ::: "memory");
    }
    __builtin_amdgcn_s_barrier();
    __builtin_amdgcn_sched_barrier(0);

    const int sblk = (t < n0) ? t : (s1off + t);
    const int s0 = sblk * 32;
    const int tbw = ((t < n0) ? b0 : b1) * 128 + 32 * w;
    const bool act0 = s0 < tbw + 16;        // tile m=0 (rows tbw..+15)
    const bool act1 = s0 < tbw + 32;        // tile m=1 (rows tbw+16..+31)

    if (act1) {
      // ---- QK^T swapped: S'[s][t] = K·Q^T; kf shared across both t-tiles ----
      f32x4 s1a = fzero, s1b = fzero, s0a = fzero, s0b = fzero;
#pragma unroll
      for (int ks = 0; ks < 4; ++ks) {
        bf16x8 kf0 = *(const bf16x8*)&k_lds[buf][ks * 512 + lane * 8];
        bf16x8 kf1 = *(const bf16x8*)&k_lds[buf][(4 + ks) * 512 + lane * 8];
        bf16x8 qm1 = __builtin_bit_cast(bf16x8, q0[1][ks]);
        s1a = __builtin_amdgcn_mfma_f32_16x16x32_bf16(kf0, qm1, s1a, 0, 0, 0);
        s1b = __builtin_amdgcn_mfma_f32_16x16x32_bf16(kf1, qm1, s1b, 0, 0, 0);
        if (act0) {
          bf16x8 qm0 = __builtin_bit_cast(bf16x8, q0[0][ks]);
          s0a = __builtin_amdgcn_mfma_f32_16x16x32_bf16(kf0, qm0, s0a, 0, 0, 0);
          s0b = __builtin_amdgcn_mfma_f32_16x16x32_bf16(kf1, qm0, s0b, 0, 0, 0);
        }
      }
      // ---- mask (keep s < t) + pack + b64 store, per tile ----
      auto maskStore = [&](f32x4 sa, f32x4 sb, int m) {
        const int tbm = tbw + 16 * m;
        if (s0 + 32 > tbm) {
          const int tcol = tbm + lh;
#pragma unroll
          for (int r = 0; r < 4; ++r) {
            if (s0 + 4 * lg + r >= tcol) sa[r] = 0.f;
            if (s0 + 16 + 4 * lg + r >= tcol) sb[r] = 0.f;
          }
        }
        u32x2 pk0, pk1;
        pk0[0] = bf16rne(sa[0]) | (bf16rne(sa[1]) << 16);
        pk0[1] = bf16rne(sa[2]) | (bf16rne(sa[3]) << 16);
        pk1[0] = bf16rne(sb[0]) | (bf16rne(sb[1]) << 16);
        pk1[1] = bf16rne(sb[2]) | (bf16rne(sb[3]) << 16);
        const int sb_ = (w * 2 + m) * 512 + lh * 8 + (lg >> 1) * 128 + (lg & 1) * 4;
        *(u32x2*)&s_lds[sb_] = pk0;
        *(u32x2*)&s_lds[sb_ + 256] = pk1;
      };
      maskStore(s1a, s1b, 1);
      if (act0) maskStore(s0a, s0b, 0);

      // ---- PV: O += P·V ; vf shared across both t-tiles ----
      bf16x8 pa1 = *(const bf16x8*)&s_lds[(w * 2 + 1) * 512 + lane * 8];
      bf16x8 pa0 = pa1;
      if (act0) pa0 = *(const bf16x8*)&s_lds[(w * 2) * 512 + lane * 8];
#pragma unroll
      for (int df = 0; df < 8; ++df) {
        bf16x8 vf = *(const bf16x8*)&v_lds[buf][df * 512 + lane * 8];
        o[1][df] = __builtin_amdgcn_mfma_f32_16x16x32_bf16(pa1, vf, o[1][df], 0, 0, 0);
        if (act0)
          o[0][df] = __builtin_amdgcn_mfma_f32_16x16x32_bf16(pa0, vf, o[0][df], 0, 0, 0);
      }
    }
    asm volatile("s_waitcnt lgkmcnt(0)" ::: "memory");
    __builtin_amdgcn_sched_barrier(0);
    __builtin_amdgcn_s_barrier();   // buf free for overwrite next step
  }

  flushO(b1);
}

extern "C" void kernel_launch(void* const* d_in, const int* in_sizes, int n_in,
                              void* d_out, int out_size, void* d_ws, size_t ws_size,
                              hipStream_t stream) {
  const float* Q = (const float*)d_in[0];
  const float* V = (const float*)d_in[1];
  const float* freqs = (const float*)d_in[2];
  float* out = (float*)d_out;

  unsigned short* qr = (unsigned short*)d_ws;                        // 32 MB
  unsigned short* vt = qr + (size_t)NH * T_DIM * N_DIM;              // 8 MB

  hipMemsetAsync(out, 0, (size_t)NH * T_DIM * DV_DIM * sizeof(float), stream);
  hipLaunchKernelGGL(rope_kernel, dim3(2048), dim3(256), 0, stream,
                     Q, freqs, (unsigned int*)qr);
  hipLaunchKernelGGL(vtrans_kernel, dim3(NH * 64), dim3(256), 0, stream, V, vt);
  hipLaunchKernelGGL(attn_kernel, dim3(1024), dim3(256), 0, stream, qr, vt, out);
}

// Round 14
// 121.064 us; speedup vs baseline: 2.0024x; 2.0024x over previous
//
#include <hip/hip_runtime.h>
#include <hip/hip_bf16.h>
#include <stdint.h>

#define T_DIM 2048
#define N_DIM 512
#define DV_DIM 128
#define NH 16          // B*H

typedef __bf16 bf16x8 __attribute__((ext_vector_type(8)));
typedef float f32x4 __attribute__((ext_vector_type(4)));
typedef float f32x2 __attribute__((ext_vector_type(2)));
typedef unsigned int u32x2 __attribute__((ext_vector_type(2)));
typedef unsigned int u32x4 __attribute__((ext_vector_type(4)));

__device__ __forceinline__ unsigned bf16rne(float x) {
  unsigned u = __builtin_bit_cast(unsigned, x);
  return (u + 0x7FFFu + ((u >> 16) & 1u)) >> 16;
}

// ---------------- RoPE: Q fp32 -> QR bf16  [bh][t][n] ----------------
__global__ void rope_kernel(const float* __restrict__ Q, const float* __restrict__ freqs,
                            unsigned int* __restrict__ qrOut) {
  const int total = NH * T_DIM * (N_DIM / 2);  // pairs
  for (int p = blockIdx.x * blockDim.x + threadIdx.x; p < total;
       p += gridDim.x * blockDim.x) {
    int n2 = p & 255;            // N/2 = 256
    int t = (p >> 8) & 2047;
    float f = freqs[2 * n2];
    f32x2 q = *(const f32x2*)(Q + 2 * (size_t)p);
    float ph = (float)t * f;
    ph = ph - floorf(ph);                 // revolutions in [0,1)
    float sn = __builtin_amdgcn_sinf(ph);
    float cn = __builtin_amdgcn_cosf(ph);
    float o0 = q.x * cn - q.y * sn;
    float o1 = q.y * cn + q.x * sn;
    qrOut[p] = bf16rne(o0) | (bf16rne(o1) << 16);
  }
}

// ---------------- transpose: qr [bh][t][n] -> qrT [bh][n][t] ----------------
__global__ void trans_kernel(const unsigned short* __restrict__ qr,
                             unsigned short* __restrict__ qrT) {
  __shared__ unsigned short tile[64][65];
  const int blk = blockIdx.x;          // bh*256 + tt*8 + nn
  const int bh = blk >> 8;
  const int tt = (blk >> 3) & 31;
  const int nn = blk & 7;
  const int t0 = tt * 64, n0 = nn * 64;
  const unsigned short* src = qr + ((size_t)bh * T_DIM + t0) * N_DIM + n0;
  const int tid = threadIdx.x;
  const int r4 = tid >> 6, cc = tid & 63;
#pragma unroll
  for (int it = 0; it < 16; ++it) {
    int r = it * 4 + r4;
    tile[r][cc] = src[(size_t)r * N_DIM + cc];
  }
  __syncthreads();
  unsigned short* dst = qrT + ((size_t)bh * N_DIM + n0) * T_DIM + t0;
#pragma unroll
  for (int it = 0; it < 16; ++it) {
    int r = it * 4 + r4;
    dst[(size_t)r * T_DIM + cc] = tile[cc][r];
  }
}

// ---- V fp32 [bh][t][d] -> frag-linear bf16 blocks (16x16x32 B-frag):
// vt[bh][sblk32][slot=df*64+lane][i] = V[s0+8*(lane>>4)+i][16*df+(lane&15)]
__global__ void vtrans_kernel(const float* __restrict__ V, unsigned short* __restrict__ vt32) {
  __shared__ unsigned short tile[32][128];
  const int blk = blockIdx.x;
  const int bh = blk >> 6;
  const int sb = blk & 63;
  const float* src = V + ((size_t)bh * T_DIM + sb * 32) * DV_DIM;
  const int tid = threadIdx.x;
#pragma unroll
  for (int i = 0; i < 16; ++i) {
    int idx = i * 256 + tid;
    tile[idx >> 7][idx & 127] = (unsigned short)bf16rne(src[idx]);
  }
  __syncthreads();
  unsigned short* dst = vt32 + (size_t)blk * 4096;
#pragma unroll
  for (int jj = 0; jj < 2; ++jj) {
    int j = jj * 256 + tid;
    int df = j >> 6, ln = j & 63;
    int lh2 = ln & 15, lg2 = ln >> 4;
    unsigned short tmp[8];
#pragma unroll
    for (int i = 0; i < 8; ++i) tmp[i] = tile[8 * lg2 + i][16 * df + lh2];
    *(u32x4*)(dst + j * 8) = *(u32x4*)tmp;
  }
}

// ---------------- fused G + exclusive prefix -> H ----------------
// H[t] = sum_{chunks k < i} QR_k^T V_k. 256 wgs x 256 thr; wg = (bh, nsl, dsl):
// slab 128n x 32d held fp32 in registers across the 16-chunk serial loop.
// Emits H_ch (bf16, B-frag-linear [nblk][slot=df*64+lane][i]) BEFORE adding
// G_ch, so H is exclusive. A = qrT frags, B = vt frags (direct global reads).
__global__ __launch_bounds__(256, 1)
void hprefix_kernel(const unsigned short* __restrict__ qrT,
                    const unsigned short* __restrict__ vt,
                    unsigned short* __restrict__ H) {
  const int bid = blockIdx.x;
  const int bh = bid >> 4;
  const int nsl = (bid >> 2) & 3;
  const int dsl = bid & 3;
  const int tid = threadIdx.x;
  const int w = tid >> 6;
  const int lane = tid & 63;
  const int lh = lane & 15, lg = lane >> 4;

  const unsigned short* qrT_h = qrT + (size_t)bh * (N_DIM * T_DIM);
  const unsigned short* vt_h = vt + (size_t)bh * (64 * 4096);
  unsigned short* H_h = H + (size_t)bh * (16 * 65536);

  const f32x4 fzero = {0.f, 0.f, 0.f, 0.f};
  f32x4 acc00 = fzero, acc01 = fzero, acc10 = fzero, acc11 = fzero;

  for (int ch = 0; ch < 16; ++ch) {
    // ---- emit H_ch = prefix so far (exclusive) ----
#pragma unroll
    for (int nf = 0; nf < 2; ++nf)
#pragma unroll
      for (int dfl = 0; dfl < 2; ++dfl) {
        const f32x4 a = (nf == 0) ? (dfl == 0 ? acc00 : acc01)
                                  : (dfl == 0 ? acc10 : acc11);
        int nloc = w * 32 + nf * 16 + 4 * lg;        // 0..124 within slab
        int nblk = nsl * 4 + (nloc >> 5);
        int lg2 = (nloc >> 3) & 3;
        int i0 = nloc & 7;                            // 0 or 4
        int df = dsl * 2 + dfl;
        int slot = df * 64 + lg2 * 16 + lh;
        u32x2 pk;
        pk[0] = bf16rne(a[0]) | (bf16rne(a[1]) << 16);
        pk[1] = bf16rne(a[2]) | (bf16rne(a[3]) << 16);
        *(u32x2*)(H_h + (size_t)ch * 65536 + nblk * 4096 + slot * 8 + i0) = pk;
      }
    // ---- accumulate G_ch ----
#pragma unroll
    for (int ks = 0; ks < 4; ++ks) {
      u32x4 a0, a1, b0, b1;
      {
        const unsigned short* pa = qrT_h + (size_t)(nsl * 128 + w * 32 + lh) * T_DIM
                                   + ch * 128 + ks * 32 + lg * 8;
        a0 = *(const u32x4*)pa;
        a1 = *(const u32x4*)(pa + 16 * T_DIM);
        const unsigned short* pb = vt_h + (size_t)(ch * 4 + ks) * 4096
                                   + ((dsl * 2) * 64 + lane) * 8;
        b0 = *(const u32x4*)pb;
        b1 = *(const u32x4*)(pb + 512);
      }
      acc00 = __builtin_amdgcn_mfma_f32_16x16x32_bf16(__builtin_bit_cast(bf16x8, a0), __builtin_bit_cast(bf16x8, b0), acc00, 0, 0, 0);
      acc01 = __builtin_amdgcn_mfma_f32_16x16x32_bf16(__builtin_bit_cast(bf16x8, a0), __builtin_bit_cast(bf16x8, b1), acc01, 0, 0, 0);
      acc10 = __builtin_amdgcn_mfma_f32_16x16x32_bf16(__builtin_bit_cast(bf16x8, a1), __builtin_bit_cast(bf16x8, b0), acc10, 0, 0, 0);
      acc11 = __builtin_amdgcn_mfma_f32_16x16x32_bf16(__builtin_bit_cast(bf16x8, a1), __builtin_bit_cast(bf16x8, b1), acc11, 0, 0, 0);
    }
  }
}

// ---------------- per-chunk output: O = QR_i H_i + tril(QR_i QR_i^T,-1) V_i ----------------
// 1024 wgs x 128 thr (2 waves, barrier-free). wg = (head pinned to XCD via
// bid&7, chunk ch, quarter q). Wave w owns 16 t-rows (tb). All B-operands
// read as u32x4 frags directly from global (L2-resident): H-frags (QH),
// qr s-rows (QK, swapped), vt-frags (PV). S->P via per-wave p_lds (no
// cross-wave traffic). Output: plain coalesced stores, no atomics.
__global__ __launch_bounds__(128, 2)
void chunk_kernel(const unsigned short* __restrict__ qr,
                  const unsigned short* __restrict__ vt,
                  const unsigned short* __restrict__ H,
                  float* __restrict__ out) {
  __shared__ unsigned short p_lds[2][2048];   // [wave][f<4][lane*8]

  const int tid = threadIdx.x;
  const int w = tid >> 6;
  const int lane = tid & 63;
  const int lh = lane & 15, lg = lane >> 4;

  const int bid = blockIdx.x;
  const int x = bid & 7;
  const int rest = bid >> 3;
  const int head = x + 8 * (rest & 1);   // 2 heads per XCD
  const int rest2 = rest >> 1;           // 0..63
  const int ch = rest2 & 15;
  const int q = rest2 >> 4;              // quarter 0..3
  const int tq = q * 32 + w * 16;        // t local to chunk
  const int tb = ch * 128 + tq;          // global t base of this wave

  const unsigned short* qr_h = qr + (size_t)head * (T_DIM * N_DIM);
  const unsigned short* vt_h = vt + (size_t)head * (64 * 4096);
  const unsigned short* H_c = H + ((size_t)head * 16 + ch) * 65536;
  float* out_h = out + (size_t)head * (T_DIM * DV_DIM);

  // Q fragments: row = t = tb+lh, k = n = 32ks + 8lg + i. Dual-use:
  // A-operand for QH (row=t), B-operand for QK swapped (col=t).
  u32x4 qf[16];
  {
    const unsigned short* pq = qr_h + (size_t)(tb + lh) * N_DIM + lg * 8;
#pragma unroll
    for (int ks = 0; ks < 16; ++ks) qf[ks] = *(const u32x4*)(pq + ks * 32);
  }

  const f32x4 fzero = {0.f, 0.f, 0.f, 0.f};
  f32x4 o[8];
#pragma unroll
  for (int df = 0; df < 8; ++df) o[df] = fzero;

  // ---- QH: O += QR_i * H_i  (skip for chunk 0: H_0 = 0) ----
  if (ch > 0) {
#pragma unroll
    for (int ks = 0; ks < 16; ++ks) {
      const unsigned short* hb = H_c + ks * 4096 + lane * 8;
      bf16x8 qa = __builtin_bit_cast(bf16x8, qf[ks]);
#pragma unroll
      for (int df = 0; df < 8; ++df) {
        bf16x8 hf = *(const bf16x8*)(hb + df * 512);
        o[df] = __builtin_amdgcn_mfma_f32_16x16x32_bf16(qa, hf, o[df], 0, 0, 0);
      }
    }
  }

  // ---- QK swapped (S'[s][t] = K.Q^T) + strict mask + pack to p_lds ----
  for (int sb = 0; sb <= q; ++sb) {
    f32x4 sA = fzero, sB = fzero;
    const unsigned short* pk0 = qr_h + (size_t)(ch * 128 + sb * 32 + lh) * N_DIM + lg * 8;
    const unsigned short* pk1 = pk0 + 16 * N_DIM;
#pragma unroll
    for (int ks = 0; ks < 16; ++ks) {
      bf16x8 kf0 = *(const bf16x8*)(pk0 + ks * 32);
      bf16x8 kf1 = *(const bf16x8*)(pk1 + ks * 32);
      bf16x8 qb = __builtin_bit_cast(bf16x8, qf[ks]);
      sA = __builtin_amdgcn_mfma_f32_16x16x32_bf16(kf0, qb, sA, 0, 0, 0);
      sB = __builtin_amdgcn_mfma_f32_16x16x32_bf16(kf1, qb, sB, 0, 0, 0);
    }
    // acc: col = t = lh, row = s = sb*32 (+16 for sB) + 4lg + r
    const int tloc = tq + lh;
#pragma unroll
    for (int r = 0; r < 4; ++r) {
      if (sb * 32 + 4 * lg + r >= tloc) sA[r] = 0.f;
      if (sb * 32 + 16 + 4 * lg + r >= tloc) sB[r] = 0.f;
    }
    u32x2 pkA, pkB;
    pkA[0] = bf16rne(sA[0]) | (bf16rne(sA[1]) << 16);
    pkA[1] = bf16rne(sA[2]) | (bf16rne(sA[3]) << 16);
    pkB[0] = bf16rne(sB[0]) | (bf16rne(sB[1]) << 16);
    pkB[1] = bf16rne(sB[2]) | (bf16rne(sB[3]) << 16);
    // P A-frag-linear: element (row=t=lh, k=s): frag f = s>>5,
    // within: lg2 = (s&31)>>3, i = s&7
    const int sa_in = 4 * lg;            // sf=0
    const int sb_in = 16 + 4 * lg;       // sf=1
    *(u32x2*)&p_lds[w][sb * 512 + ((sa_in >> 3) * 16 + lh) * 8 + (sa_in & 7)] = pkA;
    *(u32x2*)&p_lds[w][sb * 512 + ((sb_in >> 3) * 16 + lh) * 8 + (sb_in & 7)] = pkB;
  }

  // ---- PV: O += P * V_i ----
  for (int f = 0; f <= q; ++f) {
    bf16x8 pa = *(const bf16x8*)&p_lds[w][f * 512 + lane * 8];
    const unsigned short* vb = vt_h + (size_t)(ch * 4 + f) * 4096 + lane * 8;
#pragma unroll
    for (int df = 0; df < 8; ++df) {
      bf16x8 vf = *(const bf16x8*)(vb + df * 512);
      o[df] = __builtin_amdgcn_mfma_f32_16x16x32_bf16(pa, vf, o[df], 0, 0, 0);
    }
  }

  // ---- epilogue: plain stores, each output element written exactly once ----
  float* ob = out_h + (size_t)(tb + 4 * lg) * DV_DIM + lh;
#pragma unroll
  for (int df = 0; df < 8; ++df)
#pragma unroll
    for (int r = 0; r < 4; ++r)
      ob[(size_t)r * DV_DIM + df * 16] = o[df][r];
}

extern "C" void kernel_launch(void* const* d_in, const int* in_sizes, int n_in,
                              void* d_out, int out_size, void* d_ws, size_t ws_size,
                              hipStream_t stream) {
  const float* Q = (const float*)d_in[0];
  const float* V = (const float*)d_in[1];
  const float* freqs = (const float*)d_in[2];
  float* out = (float*)d_out;

  unsigned short* qr = (unsigned short*)d_ws;                 // 33.5 MB
  unsigned short* qrT = qr + (size_t)16777216;                // 33.5 MB
  unsigned short* vt = qrT + (size_t)16777216;                // 8.4 MB
  unsigned short* H = vt + (size_t)4194304;                   // 33.5 MB

  hipLaunchKernelGGL(rope_kernel, dim3(2048), dim3(256), 0, stream,
                     Q, freqs, (unsigned int*)qr);
  hipLaunchKernelGGL(trans_kernel, dim3(4096), dim3(256), 0, stream, qr, qrT);
  hipLaunchKernelGGL(vtrans_kernel, dim3(NH * 64), dim3(256), 0, stream, V, vt);
  hipLaunchKernelGGL(hprefix_kernel, dim3(256), dim3(256), 0, stream, qrT, vt, H);
  hipLaunchKernelGGL(chunk_kernel, dim3(1024), dim3(128), 0, stream, qr, vt, H, out);
}

// Round 15
// 107.628 us; speedup vs baseline: 2.2523x; 1.1248x over previous
//
#include <hip/hip_runtime.h>
#include <hip/hip_bf16.h>
#include <stdint.h>

#define T_DIM 2048
#define N_DIM 512
#define DV_DIM 128
#define NH 16          // B*H

typedef __bf16 bf16x8 __attribute__((ext_vector_type(8)));
typedef float f32x4 __attribute__((ext_vector_type(4)));
typedef float f32x2 __attribute__((ext_vector_type(2)));
typedef unsigned int u32x2 __attribute__((ext_vector_type(2)));
typedef unsigned int u32x4 __attribute__((ext_vector_type(4)));

__device__ __forceinline__ unsigned bf16rne(float x) {
  unsigned u = __builtin_bit_cast(unsigned, x);
  return (u + 0x7FFFu + ((u >> 16) & 1u)) >> 16;
}

// ---------------- fused RoPE + transpose ----------------
// Q fp32 [bh][t][n] -> qr bf16 [bh][t][n] AND qrT bf16 [bh][n][t].
// 4096 wgs x 256 thr; bh pinned to XCD bh%8 (bid&7) so qr/qrT lines live in
// the L2 that chunk/hprefix (same pinning) will read them from.
__global__ void ropeT_kernel(const float* __restrict__ Q, const float* __restrict__ freqs,
                             unsigned int* __restrict__ qrOut,
                             unsigned int* __restrict__ qrTOut) {
  __shared__ unsigned short tile[64][65];
  const int bid = blockIdx.x;
  const int k = bid >> 3;
  const int bh = (bid & 7) + 8 * (k & 1);
  const int rest = k >> 1;             // 0..255
  const int tt = rest >> 3;            // 0..31
  const int nn = rest & 7;             // 0..7
  const int t0 = tt * 64, n0 = nn * 64;
  const int tid = threadIdx.x;

  const float* src = Q + ((size_t)bh * T_DIM + t0) * N_DIM + n0;
  unsigned int* qrb = qrOut + ((size_t)bh * T_DIM + t0) * 256 + (n0 >> 1);
#pragma unroll
  for (int it = 0; it < 8; ++it) {
    int pi = it * 256 + tid;           // 0..2047 pairs in 64x64 tile
    int r = pi >> 5;                   // t-local
    int c2 = pi & 31;                  // pair col
    float f = freqs[n0 + 2 * c2];
    f32x2 qv = *(const f32x2*)(src + (size_t)r * N_DIM + 2 * c2);
    float ph = (float)(t0 + r) * f;
    ph = ph - floorf(ph);              // revolutions in [0,1)
    float sn = __builtin_amdgcn_sinf(ph);
    float cn = __builtin_amdgcn_cosf(ph);
    unsigned lo = bf16rne(qv.x * cn - qv.y * sn);
    unsigned hi = bf16rne(qv.y * cn + qv.x * sn);
    qrb[(size_t)r * 256 + c2] = lo | (hi << 16);
    tile[r][2 * c2] = (unsigned short)lo;
    tile[r][2 * c2 + 1] = (unsigned short)hi;
  }
  __syncthreads();
  unsigned int* dstb = qrTOut + ((size_t)bh * N_DIM + n0) * 1024 + (t0 >> 1);
#pragma unroll
  for (int it = 0; it < 8; ++it) {
    int slot = it * 256 + tid;         // 0..2047
    int rn = slot >> 5;                // n-local 0..63
    int c2 = slot & 31;                // t-pair 0..31
    unsigned lo = tile[2 * c2][rn];
    unsigned hi = tile[2 * c2 + 1][rn];
    dstb[(size_t)rn * 1024 + c2] = lo | (hi << 16);
  }
}

// ---- V fp32 [bh][t][d] -> frag-linear bf16 blocks (16x16x32 B-frag):
// vt[bh][sblk32][slot=df*64+lane][i] = V[s0+8*(lane>>4)+i][16*df+(lane&15)]
// bh pinned to XCD bh%8.
__global__ void vtrans_kernel(const float* __restrict__ V, unsigned short* __restrict__ vt32) {
  __shared__ unsigned short tile[32][128];
  const int bid = blockIdx.x;
  const int bh = (bid & 7) + 8 * ((bid >> 3) & 1);
  const int sb = bid >> 4;             // 0..63
  const float* src = V + ((size_t)bh * T_DIM + sb * 32) * DV_DIM;
  const int tid = threadIdx.x;
#pragma unroll
  for (int i = 0; i < 16; ++i) {
    int idx = i * 256 + tid;
    tile[idx >> 7][idx & 127] = (unsigned short)bf16rne(src[idx]);
  }
  __syncthreads();
  unsigned short* dst = vt32 + ((size_t)bh * 64 + sb) * 4096;
#pragma unroll
  for (int jj = 0; jj < 2; ++jj) {
    int j = jj * 256 + tid;
    int df = j >> 6, ln = j & 63;
    int lh2 = ln & 15, lg2 = ln >> 4;
    unsigned short tmp[8];
#pragma unroll
    for (int i = 0; i < 8; ++i) tmp[i] = tile[8 * lg2 + i][16 * df + lh2];
    *(u32x4*)(dst + j * 8) = *(u32x4*)tmp;
  }
}

// ---------------- fused G + exclusive prefix -> H ----------------
// H[t] = sum_{chunks k < i} QR_k^T V_k. 256 wgs x 256 thr; wg = (bh, nsl,
// dsl) with bh pinned to XCD bh%8 (so H is written on the XCD that reads it).
__global__ __launch_bounds__(256, 1)
void hprefix_kernel(const unsigned short* __restrict__ qrT,
                    const unsigned short* __restrict__ vt,
                    unsigned short* __restrict__ H) {
  const int bid = blockIdx.x;
  const int bh = (bid & 7) + 8 * ((bid >> 3) & 1);
  const int slab = bid >> 4;           // 0..15
  const int nsl = slab >> 2;
  const int dsl = slab & 3;
  const int tid = threadIdx.x;
  const int w = tid >> 6;
  const int lane = tid & 63;
  const int lh = lane & 15, lg = lane >> 4;

  const unsigned short* qrT_h = qrT + (size_t)bh * (N_DIM * T_DIM);
  const unsigned short* vt_h = vt + (size_t)bh * (64 * 4096);
  unsigned short* H_h = H + (size_t)bh * (16 * 65536);

  const f32x4 fzero = {0.f, 0.f, 0.f, 0.f};
  f32x4 acc00 = fzero, acc01 = fzero, acc10 = fzero, acc11 = fzero;

  for (int ch = 0; ch < 16; ++ch) {
    // ---- emit H_ch = prefix so far (exclusive) ----
#pragma unroll
    for (int nf = 0; nf < 2; ++nf)
#pragma unroll
      for (int dfl = 0; dfl < 2; ++dfl) {
        const f32x4 a = (nf == 0) ? (dfl == 0 ? acc00 : acc01)
                                  : (dfl == 0 ? acc10 : acc11);
        int nloc = w * 32 + nf * 16 + 4 * lg;
        int nblk = nsl * 4 + (nloc >> 5);
        int lg2 = (nloc >> 3) & 3;
        int i0 = nloc & 7;
        int df = dsl * 2 + dfl;
        int slot = df * 64 + lg2 * 16 + lh;
        u32x2 pk;
        pk[0] = bf16rne(a[0]) | (bf16rne(a[1]) << 16);
        pk[1] = bf16rne(a[2]) | (bf16rne(a[3]) << 16);
        *(u32x2*)(H_h + (size_t)ch * 65536 + nblk * 4096 + slot * 8 + i0) = pk;
      }
    // ---- accumulate G_ch ----
#pragma unroll
    for (int ks = 0; ks < 4; ++ks) {
      u32x4 a0, a1, b0, b1;
      {
        const unsigned short* pa = qrT_h + (size_t)(nsl * 128 + w * 32 + lh) * T_DIM
                                   + ch * 128 + ks * 32 + lg * 8;
        a0 = *(const u32x4*)pa;
        a1 = *(const u32x4*)(pa + 16 * T_DIM);
        const unsigned short* pb = vt_h + (size_t)(ch * 4 + ks) * 4096
                                   + ((dsl * 2) * 64 + lane) * 8;
        b0 = *(const u32x4*)pb;
        b1 = *(const u32x4*)(pb + 512);
      }
      acc00 = __builtin_amdgcn_mfma_f32_16x16x32_bf16(__builtin_bit_cast(bf16x8, a0), __builtin_bit_cast(bf16x8, b0), acc00, 0, 0, 0);
      acc01 = __builtin_amdgcn_mfma_f32_16x16x32_bf16(__builtin_bit_cast(bf16x8, a0), __builtin_bit_cast(bf16x8, b1), acc01, 0, 0, 0);
      acc10 = __builtin_amdgcn_mfma_f32_16x16x32_bf16(__builtin_bit_cast(bf16x8, a1), __builtin_bit_cast(bf16x8, b0), acc10, 0, 0, 0);
      acc11 = __builtin_amdgcn_mfma_f32_16x16x32_bf16(__builtin_bit_cast(bf16x8, a1), __builtin_bit_cast(bf16x8, b1), acc11, 0, 0, 0);
    }
  }
}

// ---------------- per-chunk output: O = QR_i H_i + tril(QR_i QR_i^T,-1) V_i ----------------
// 2048 wgs x 128 thr (2 waves, barrier-free). wg = (head pinned to XCD,
// chunk ch, quarter q, d-half dh). Each wg computes 4 of 8 d-frags (QK
// recomputed per half -> 2x TLP: 16 waves/CU). All B-operands direct global
// u32x4 frag reads, now XCD-local. Plain stores, no atomics.
__global__ __launch_bounds__(128, 4)
void chunk_kernel(const unsigned short* __restrict__ qr,
                  const unsigned short* __restrict__ vt,
                  const unsigned short* __restrict__ H,
                  float* __restrict__ out) {
  __shared__ unsigned short p_lds[2][2048];   // [wave][f<4][lane*8]

  const int tid = threadIdx.x;
  const int w = tid >> 6;
  const int lane = tid & 63;
  const int lh = lane & 15, lg = lane >> 4;

  const int bid = blockIdx.x;
  const int rest = bid >> 3;
  const int head = (bid & 7) + 8 * (rest & 1);
  const int rest2 = rest >> 1;           // 0..127
  const int ch = rest2 & 15;
  const int q = (rest2 >> 4) & 3;        // quarter
  const int dh = rest2 >> 6;             // d-half 0..1
  const int tq = q * 32 + w * 16;
  const int tb = ch * 128 + tq;

  const unsigned short* qr_h = qr + (size_t)head * (T_DIM * N_DIM);
  const unsigned short* vt_h = vt + (size_t)head * (64 * 4096);
  const unsigned short* H_c = H + ((size_t)head * 16 + ch) * 65536;
  float* out_h = out + (size_t)head * (T_DIM * DV_DIM);

  // Q fragments: row = t = tb+lh, k = n = 32ks + 8lg + i (A for QH, B for QK)
  u32x4 qf[16];
  {
    const unsigned short* pq = qr_h + (size_t)(tb + lh) * N_DIM + lg * 8;
#pragma unroll
    for (int ks = 0; ks < 16; ++ks) qf[ks] = *(const u32x4*)(pq + ks * 32);
  }

  const f32x4 fzero = {0.f, 0.f, 0.f, 0.f};
  f32x4 o[4];
#pragma unroll
  for (int df = 0; df < 4; ++df) o[df] = fzero;

  // ---- QH: O += QR_i * H_i  (skip for chunk 0: H_0 = 0) ----
  if (ch > 0) {
#pragma unroll
    for (int ks = 0; ks < 16; ++ks) {
      const unsigned short* hb = H_c + ks * 4096 + dh * 2048 + lane * 8;
      bf16x8 qa = __builtin_bit_cast(bf16x8, qf[ks]);
#pragma unroll
      for (int df = 0; df < 4; ++df) {
        bf16x8 hf = *(const bf16x8*)(hb + df * 512);
        o[df] = __builtin_amdgcn_mfma_f32_16x16x32_bf16(qa, hf, o[df], 0, 0, 0);
      }
    }
  }

  // ---- QK swapped (S'[s][t] = K.Q^T) + strict mask + pack to p_lds ----
  for (int sb = 0; sb <= q; ++sb) {
    f32x4 sA = fzero, sB = fzero;
    const unsigned short* pk0 = qr_h + (size_t)(ch * 128 + sb * 32 + lh) * N_DIM + lg * 8;
    const unsigned short* pk1 = pk0 + 16 * N_DIM;
#pragma unroll
    for (int ks = 0; ks < 16; ++ks) {
      bf16x8 kf0 = *(const bf16x8*)(pk0 + ks * 32);
      bf16x8 kf1 = *(const bf16x8*)(pk1 + ks * 32);
      bf16x8 qb = __builtin_bit_cast(bf16x8, qf[ks]);
      sA = __builtin_amdgcn_mfma_f32_16x16x32_bf16(kf0, qb, sA, 0, 0, 0);
      sB = __builtin_amdgcn_mfma_f32_16x16x32_bf16(kf1, qb, sB, 0, 0, 0);
    }
    const int tloc = tq + lh;
#pragma unroll
    for (int r = 0; r < 4; ++r) {
      if (sb * 32 + 4 * lg + r >= tloc) sA[r] = 0.f;
      if (sb * 32 + 16 + 4 * lg + r >= tloc) sB[r] = 0.f;
    }
    u32x2 pkA, pkB;
    pkA[0] = bf16rne(sA[0]) | (bf16rne(sA[1]) << 16);
    pkA[1] = bf16rne(sA[2]) | (bf16rne(sA[3]) << 16);
    pkB[0] = bf16rne(sB[0]) | (bf16rne(sB[1]) << 16);
    pkB[1] = bf16rne(sB[2]) | (bf16rne(sB[3]) << 16);
    const int sa_in = 4 * lg;
    const int sb_in = 16 + 4 * lg;
    *(u32x2*)&p_lds[w][sb * 512 + ((sa_in >> 3) * 16 + lh) * 8 + (sa_in & 7)] = pkA;
    *(u32x2*)&p_lds[w][sb * 512 + ((sb_in >> 3) * 16 + lh) * 8 + (sb_in & 7)] = pkB;
  }

  // ---- PV: O += P * V_i ----
  for (int f = 0; f <= q; ++f) {
    bf16x8 pa = *(const bf16x8*)&p_lds[w][f * 512 + lane * 8];
    const unsigned short* vb = vt_h + (size_t)(ch * 4 + f) * 4096 + dh * 2048 + lane * 8;
#pragma unroll
    for (int df = 0; df < 4; ++df) {
      bf16x8 vf = *(const bf16x8*)(vb + df * 512);
      o[df] = __builtin_amdgcn_mfma_f32_16x16x32_bf16(pa, vf, o[df], 0, 0, 0);
    }
  }

  // ---- epilogue: plain stores, each element written exactly once ----
  float* ob = out_h + (size_t)(tb + 4 * lg) * DV_DIM + dh * 64 + lh;
#pragma unroll
  for (int df = 0; df < 4; ++df)
#pragma unroll
    for (int r = 0; r < 4; ++r)
      ob[(size_t)r * DV_DIM + df * 16] = o[df][r];
}

extern "C" void kernel_launch(void* const* d_in, const int* in_sizes, int n_in,
                              void* d_out, int out_size, void* d_ws, size_t ws_size,
                              hipStream_t stream) {
  const float* Q = (const float*)d_in[0];
  const float* V = (const float*)d_in[1];
  const float* freqs = (const float*)d_in[2];
  float* out = (float*)d_out;

  unsigned short* qr = (unsigned short*)d_ws;                 // 33.5 MB
  unsigned short* qrT = qr + (size_t)16777216;                // 33.5 MB
  unsigned short* vt = qrT + (size_t)16777216;                // 8.4 MB
  unsigned short* H = vt + (size_t)4194304;                   // 33.5 MB

  hipLaunchKernelGGL(ropeT_kernel, dim3(4096), dim3(256), 0, stream,
                     Q, freqs, (unsigned int*)qr, (unsigned int*)qrT);
  hipLaunchKernelGGL(vtrans_kernel, dim3(NH * 64), dim3(256), 0, stream, V, vt);
  hipLaunchKernelGGL(hprefix_kernel, dim3(256), dim3(256), 0, stream, qrT, vt, H);
  hipLaunchKernelGGL(chunk_kernel, dim3(2048), dim3(128), 0, stream, qr, vt, H, out);
}

// Round 17
// 105.933 us; speedup vs baseline: 2.2884x; 1.0160x over previous
//
#include <hip/hip_runtime.h>
#include <hip/hip_bf16.h>
#include <stdint.h>

#define T_DIM 2048
#define N_DIM 512
#define DV_DIM 128
#define NH 16          // B*H

typedef __bf16 bf16x8 __attribute__((ext_vector_type(8)));
typedef float f32x4 __attribute__((ext_vector_type(4)));
typedef float f32x2 __attribute__((ext_vector_type(2)));
typedef unsigned int u32x2 __attribute__((ext_vector_type(2)));
typedef unsigned int u32x4 __attribute__((ext_vector_type(4)));

__device__ __forceinline__ unsigned bf16rne(float x) {
  unsigned u = __builtin_bit_cast(unsigned, x);
  return (u + 0x7FFFu + ((u >> 16) & 1u)) >> 16;
}

__device__ __forceinline__ void load_lds16(const void* g, void* l) {
  __builtin_amdgcn_global_load_lds((const __attribute__((address_space(1))) void*)g,
                                   (__attribute__((address_space(3))) void*)l, 16, 0, 0);
}

// ---------------- fused RoPE + transpose ----------------
// Q fp32 [bh][t][n] -> qr bf16 [bh][t][n] AND qrT bf16 [bh][n][t].
// bh pinned to XCD bh%8 (bid&7) matching all consumers.
__global__ void ropeT_kernel(const float* __restrict__ Q, const float* __restrict__ freqs,
                             unsigned int* __restrict__ qrOut,
                             unsigned int* __restrict__ qrTOut) {
  __shared__ unsigned short tile[64][65];
  const int bid = blockIdx.x;
  const int k = bid >> 3;
  const int bh = (bid & 7) + 8 * (k & 1);
  const int rest = k >> 1;             // 0..255
  const int tt = rest >> 3;            // 0..31
  const int nn = rest & 7;             // 0..7
  const int t0 = tt * 64, n0 = nn * 64;
  const int tid = threadIdx.x;

  const float* src = Q + ((size_t)bh * T_DIM + t0) * N_DIM + n0;
  unsigned int* qrb = qrOut + ((size_t)bh * T_DIM + t0) * 256 + (n0 >> 1);
#pragma unroll
  for (int it = 0; it < 8; ++it) {
    int pi = it * 256 + tid;           // 0..2047 pairs in 64x64 tile
    int r = pi >> 5;                   // t-local
    int c2 = pi & 31;                  // pair col
    float f = freqs[n0 + 2 * c2];
    f32x2 qv = *(const f32x2*)(src + (size_t)r * N_DIM + 2 * c2);
    float ph = (float)(t0 + r) * f;
    ph = ph - floorf(ph);              // revolutions in [0,1)
    float sn = __builtin_amdgcn_sinf(ph);
    float cn = __builtin_amdgcn_cosf(ph);
    unsigned lo = bf16rne(qv.x * cn - qv.y * sn);
    unsigned hi = bf16rne(qv.y * cn + qv.x * sn);
    qrb[(size_t)r * 256 + c2] = lo | (hi << 16);
    tile[r][2 * c2] = (unsigned short)lo;
    tile[r][2 * c2 + 1] = (unsigned short)hi;
  }
  __syncthreads();
  unsigned int* dstb = qrTOut + ((size_t)bh * N_DIM + n0) * 1024 + (t0 >> 1);
#pragma unroll
  for (int it = 0; it < 8; ++it) {
    int slot = it * 256 + tid;         // 0..2047
    int rn = slot >> 5;                // n-local 0..63
    int c2 = slot & 31;                // t-pair 0..31
    unsigned lo = tile[2 * c2][rn];
    unsigned hi = tile[2 * c2 + 1][rn];
    dstb[(size_t)rn * 1024 + c2] = lo | (hi << 16);
  }
}

// ---- V fp32 [bh][t][d] -> frag-linear bf16 blocks (16x16x32 B-frag):
// vt[bh][sblk32][slot=df*64+lane][i] = V[s0+8*(lane>>4)+i][16*df+(lane&15)]
__global__ void vtrans_kernel(const float* __restrict__ V, unsigned short* __restrict__ vt32) {
  __shared__ unsigned short tile[32][128];
  const int bid = blockIdx.x;
  const int bh = (bid & 7) + 8 * ((bid >> 3) & 1);
  const int sb = bid >> 4;             // 0..63
  const float* src = V + ((size_t)bh * T_DIM + sb * 32) * DV_DIM;
  const int tid = threadIdx.x;
#pragma unroll
  for (int i = 0; i < 16; ++i) {
    int idx = i * 256 + tid;
    tile[idx >> 7][idx & 127] = (unsigned short)bf16rne(src[idx]);
  }
  __syncthreads();
  unsigned short* dst = vt32 + ((size_t)bh * 64 + sb) * 4096;
#pragma unroll
  for (int jj = 0; jj < 2; ++jj) {
    int j = jj * 256 + tid;
    int df = j >> 6, ln = j & 63;
    int lh2 = ln & 15, lg2 = ln >> 4;
    unsigned short tmp[8];
#pragma unroll
    for (int i = 0; i < 8; ++i) tmp[i] = tile[8 * lg2 + i][16 * df + lh2];
    *(u32x4*)(dst + j * 8) = *(u32x4*)tmp;
  }
}

// ---------------- fused G + exclusive prefix -> H ----------------
// H[t] = sum_{chunks k < i} QR_k^T V_k, emitted bf16 B-frag-linear.
__global__ __launch_bounds__(256, 1)
void hprefix_kernel(const unsigned short* __restrict__ qrT,
                    const unsigned short* __restrict__ vt,
                    unsigned short* __restrict__ H) {
  const int bid = blockIdx.x;
  const int bh = (bid & 7) + 8 * ((bid >> 3) & 1);
  const int slab = bid >> 4;           // 0..15
  const int nsl = slab >> 2;
  const int dsl = slab & 3;
  const int tid = threadIdx.x;
  const int w = tid >> 6;
  const int lane = tid & 63;
  const int lh = lane & 15, lg = lane >> 4;

  const unsigned short* qrT_h = qrT + (size_t)bh * (N_DIM * T_DIM);
  const unsigned short* vt_h = vt + (size_t)bh * (64 * 4096);
  unsigned short* H_h = H + (size_t)bh * (16 * 65536);

  const f32x4 fzero = {0.f, 0.f, 0.f, 0.f};
  f32x4 acc00 = fzero, acc01 = fzero, acc10 = fzero, acc11 = fzero;

  for (int ch = 0; ch < 16; ++ch) {
    // ---- emit H_ch = prefix so far (exclusive) ----
#pragma unroll
    for (int nf = 0; nf < 2; ++nf)
#pragma unroll
      for (int dfl = 0; dfl < 2; ++dfl) {
        const f32x4 a = (nf == 0) ? (dfl == 0 ? acc00 : acc01)
                                  : (dfl == 0 ? acc10 : acc11);
        int nloc = w * 32 + nf * 16 + 4 * lg;
        int nblk = nsl * 4 + (nloc >> 5);
        int lg2 = (nloc >> 3) & 3;
        int i0 = nloc & 7;
        int df = dsl * 2 + dfl;
        int slot = df * 64 + lg2 * 16 + lh;
        u32x2 pk;
        pk[0] = bf16rne(a[0]) | (bf16rne(a[1]) << 16);
        pk[1] = bf16rne(a[2]) | (bf16rne(a[3]) << 16);
        *(u32x2*)(H_h + (size_t)ch * 65536 + nblk * 4096 + slot * 8 + i0) = pk;
      }
    // ---- accumulate G_ch ----
#pragma unroll
    for (int ks = 0; ks < 4; ++ks) {
      u32x4 a0, a1, b0, b1;
      {
        const unsigned short* pa = qrT_h + (size_t)(nsl * 128 + w * 32 + lh) * T_DIM
                                   + ch * 128 + ks * 32 + lg * 8;
        a0 = *(const u32x4*)pa;
        a1 = *(const u32x4*)(pa + 16 * T_DIM);
        const unsigned short* pb = vt_h + (size_t)(ch * 4 + ks) * 4096
                                   + ((dsl * 2) * 64 + lane) * 8;
        b0 = *(const u32x4*)pb;
        b1 = *(const u32x4*)(pb + 512);
      }
      acc00 = __builtin_amdgcn_mfma_f32_16x16x32_bf16(__builtin_bit_cast(bf16x8, a0), __builtin_bit_cast(bf16x8, b0), acc00, 0, 0, 0);
      acc01 = __builtin_amdgcn_mfma_f32_16x16x32_bf16(__builtin_bit_cast(bf16x8, a0), __builtin_bit_cast(bf16x8, b1), acc01, 0, 0, 0);
      acc10 = __builtin_amdgcn_mfma_f32_16x16x32_bf16(__builtin_bit_cast(bf16x8, a1), __builtin_bit_cast(bf16x8, b0), acc10, 0, 0, 0);
      acc11 = __builtin_amdgcn_mfma_f32_16x16x32_bf16(__builtin_bit_cast(bf16x8, a1), __builtin_bit_cast(bf16x8, b1), acc11, 0, 0, 0);
    }
  }
}

// ---------------- per-chunk output: O = QR_i H_i + tril(QR_i QR_i^T,-1) V_i ----------------
// 512 wgs = (head pinned to XCD, ch, dh) x 512 thr (8 waves; wave w owns 16
// t-rows). H dh-half (64KB) staged through LDS in two 32KB halves via
// global_load_lds (read from L2 exactly ONCE per wg); QH reads become
// conflict-free lane-linear LDS. QK (K from L2-local qr) + PV run first,
// overlapping the async first stage. Plain stores, no atomics.
__global__ __launch_bounds__(512, 4)
void chunk_kernel(const unsigned short* __restrict__ qr,
                  const unsigned short* __restrict__ vt,
                  const unsigned short* __restrict__ H,
                  float* __restrict__ out) {
  __shared__ unsigned short h_lds[16384];    // 32KB: [nb 8][256 slots x 8]
  __shared__ unsigned short p_lds[8 * 2048]; // 32KB: [wave][sb 4][A-frag 512]

  const int tid = threadIdx.x;
  const int w = tid >> 6;              // 0..7
  const int lane = tid & 63;
  const int lh = lane & 15, lg = lane >> 4;

  const int bid = blockIdx.x;
  const int y = bid >> 3;
  const int head = (bid & 7) + 8 * (y & 1);
  const int rest = y >> 1;             // 0..31
  const int ch = rest & 15;
  const int dh = rest >> 4;            // d-half

  const unsigned short* qr_h = qr + (size_t)head * (T_DIM * N_DIM);
  const unsigned short* vt_h = vt + (size_t)head * (64 * 4096);
  const unsigned short* H_c = H + ((size_t)head * 16 + ch) * 65536;
  float* out_h = out + (size_t)head * (T_DIM * DV_DIM);

  const int tq = w * 16;               // t local to chunk
  const int tb = ch * 128 + tq;
  const int nsb = (w >> 1) + 1;        // causal 32-s blocks for this wave

  // stage 8 n-blocks of H (dh half): each block's dh-half = 256 slots of 16B.
  // LDS dest: wave-uniform base + lane*16 (linear); global src per-lane.
  auto stageH = [&](int half) {
#pragma unroll
    for (int it = 0; it < 4; ++it) {
      int s = it * 512 + tid;          // 0..2047 slots of 16B
      int nb = half * 8 + (s >> 8);    // 256 slots per n-block
      const unsigned short* src = H_c + nb * 4096 + dh * 2048 + (s & 255) * 8;
      load_lds16(src, (char*)h_lds + s * 16);
    }
  };

  stageH(0);   // async: consumed only after the first __syncthreads below

  // ---- Q fragments: row = t = tb+lh, k = 32ks+8lg+i (A for QH, B for QK) ----
  u32x4 qf[16];
  {
    const unsigned short* pq = qr_h + (size_t)(tb + lh) * N_DIM + lg * 8;
#pragma unroll
    for (int ks = 0; ks < 16; ++ks) qf[ks] = *(const u32x4*)(pq + ks * 32);
  }

  const f32x4 fzero = {0.f, 0.f, 0.f, 0.f};
  f32x4 o[4];
#pragma unroll
  for (int df = 0; df < 4; ++df) o[df] = fzero;

  // ---- QK swapped (S'[s][t] = K.Q^T) + strict mask + pack to p_lds ----
  for (int sb = 0; sb < nsb; ++sb) {
    f32x4 sA = fzero, sB = fzero;
    const unsigned short* pk0 = qr_h + (size_t)(ch * 128 + sb * 32 + lh) * N_DIM + lg * 8;
    const unsigned short* pk1 = pk0 + 16 * N_DIM;
#pragma unroll
    for (int ks = 0; ks < 16; ++ks) {
      bf16x8 kf0 = *(const bf16x8*)(pk0 + ks * 32);
      bf16x8 kf1 = *(const bf16x8*)(pk1 + ks * 32);
      bf16x8 qb = __builtin_bit_cast(bf16x8, qf[ks]);
      sA = __builtin_amdgcn_mfma_f32_16x16x32_bf16(kf0, qb, sA, 0, 0, 0);
      sB = __builtin_amdgcn_mfma_f32_16x16x32_bf16(kf1, qb, sB, 0, 0, 0);
    }
    const int tloc = tq + lh;
#pragma unroll
    for (int r = 0; r < 4; ++r) {
      if (sb * 32 + 4 * lg + r >= tloc) sA[r] = 0.f;
      if (sb * 32 + 16 + 4 * lg + r >= tloc) sB[r] = 0.f;
    }
    u32x2 pkA, pkB;
    pkA[0] = bf16rne(sA[0]) | (bf16rne(sA[1]) << 16);
    pkA[1] = bf16rne(sA[2]) | (bf16rne(sA[3]) << 16);
    pkB[0] = bf16rne(sB[0]) | (bf16rne(sB[1]) << 16);
    pkB[1] = bf16rne(sB[2]) | (bf16rne(sB[3]) << 16);
    const int sa_in = 4 * lg;
    const int sb_in = 16 + 4 * lg;
    *(u32x2*)&p_lds[w * 2048 + sb * 512 + ((sa_in >> 3) * 16 + lh) * 8 + (sa_in & 7)] = pkA;
    *(u32x2*)&p_lds[w * 2048 + sb * 512 + ((sb_in >> 3) * 16 + lh) * 8 + (sb_in & 7)] = pkB;
  }

  // ---- PV: O += P * V_i (vt frags from L2-local global) ----
  for (int f = 0; f < nsb; ++f) {
    bf16x8 pa = *(const bf16x8*)&p_lds[w * 2048 + f * 512 + lane * 8];
    const unsigned short* vb = vt_h + (size_t)(ch * 4 + f) * 4096 + dh * 2048 + lane * 8;
#pragma unroll
    for (int df = 0; df < 4; ++df) {
      bf16x8 vf = *(const bf16x8*)(vb + df * 512);
      o[df] = __builtin_amdgcn_mfma_f32_16x16x32_bf16(pa, vf, o[df], 0, 0, 0);
    }
  }

  // ---- QH half A: n = 0..255 from LDS (stage0 landed at this barrier) ----
  __syncthreads();
  if (ch > 0) {
#pragma unroll
    for (int ks = 0; ks < 8; ++ks) {
      bf16x8 qa = __builtin_bit_cast(bf16x8, qf[ks]);
      const unsigned short* hb = h_lds + ks * 2048 + lane * 8;
#pragma unroll
      for (int df = 0; df < 4; ++df) {
        bf16x8 hf = *(const bf16x8*)(hb + df * 512);
        o[df] = __builtin_amdgcn_mfma_f32_16x16x32_bf16(qa, hf, o[df], 0, 0, 0);
      }
    }
  }
  __syncthreads();           // all waves done reading half A
  stageH(1);
  __syncthreads();           // stage1 landed
  if (ch > 0) {
#pragma unroll
    for (int ks = 0; ks < 8; ++ks) {
      bf16x8 qa = __builtin_bit_cast(bf16x8, qf[8 + ks]);
      const unsigned short* hb = h_lds + ks * 2048 + lane * 8;
#pragma unroll
      for (int df = 0; df < 4; ++df) {
        bf16x8 hf = *(const bf16x8*)(hb + df * 512);
        o[df] = __builtin_amdgcn_mfma_f32_16x16x32_bf16(qa, hf, o[df], 0, 0, 0);
      }
    }
  }

  // ---- epilogue: plain stores, each element written exactly once ----
  float* ob = out_h + (size_t)(tb + 4 * lg) * DV_DIM + dh * 64 + lh;
#pragma unroll
  for (int df = 0; df < 4; ++df)
#pragma unroll
    for (int r = 0; r < 4; ++r)
      ob[(size_t)r * DV_DIM + df * 16] = o[df][r];
}

extern "C" void kernel_launch(void* const* d_in, const int* in_sizes, int n_in,
                              void* d_out, int out_size, void* d_ws, size_t ws_size,
                              hipStream_t stream) {
  const float* Q = (const float*)d_in[0];
  const float* V = (const float*)d_in[1];
  const float* freqs = (const float*)d_in[2];
  float* out = (float*)d_out;

  unsigned short* qr = (unsigned short*)d_ws;                 // 33.5 MB
  unsigned short* qrT = qr + (size_t)16777216;                // 33.5 MB
  unsigned short* vt = qrT + (size_t)16777216;                // 8.4 MB
  unsigned short* H = vt + (size_t)4194304;                   // 33.5 MB

  hipLaunchKernelGGL(ropeT_kernel, dim3(4096), dim3(256), 0, stream,
                     Q, freqs, (unsigned int*)qr, (unsigned int*)qrT);
  hipLaunchKernelGGL(vtrans_kernel, dim3(NH * 64), dim3(256), 0, stream, V, vt);
  hipLaunchKernelGGL(hprefix_kernel, dim3(256), dim3(256), 0, stream, qrT, vt, H);
  hipLaunchKernelGGL(chunk_kernel, dim3(512), dim3(512), 0, stream, qr, vt, H, out);
}

// Round 18
// 79.934 us; speedup vs baseline: 3.0327x; 1.3253x over previous
//
#include <hip/hip_runtime.h>
#include <hip/hip_bf16.h>
#include <stdint.h>

#define T_DIM 2048
#define N_DIM 512
#define DV_DIM 128
#define NH 16          // B*H

typedef __bf16 bf16x8 __attribute__((ext_vector_type(8)));
typedef float f32x4 __attribute__((ext_vector_type(4)));
typedef float f32x2 __attribute__((ext_vector_type(2)));
typedef unsigned int u32x2 __attribute__((ext_vector_type(2)));
typedef unsigned int u32x4 __attribute__((ext_vector_type(4)));

__device__ __forceinline__ unsigned bf16rne(float x) {
  unsigned u = __builtin_bit_cast(unsigned, x);
  return (u + 0x7FFFu + ((u >> 16) & 1u)) >> 16;
}

__device__ __forceinline__ void load_lds16(const void* g, void* l) {
  __builtin_amdgcn_global_load_lds((const __attribute__((address_space(1))) void*)g,
                                   (__attribute__((address_space(3))) void*)l, 16, 0, 0);
}

// ---------------- fused RoPE + transpose ----------------
// Q fp32 [bh][t][n] -> qr bf16 [bh][t][n] AND qrT bf16 [bh][n][t].
// bh pinned to XCD bh%8 (bid&7) matching all consumers.
__global__ void ropeT_kernel(const float* __restrict__ Q, const float* __restrict__ freqs,
                             unsigned int* __restrict__ qrOut,
                             unsigned int* __restrict__ qrTOut) {
  __shared__ unsigned short tile[64][65];
  const int bid = blockIdx.x;
  const int k = bid >> 3;
  const int bh = (bid & 7) + 8 * (k & 1);
  const int rest = k >> 1;             // 0..255
  const int tt = rest >> 3;            // 0..31
  const int nn = rest & 7;             // 0..7
  const int t0 = tt * 64, n0 = nn * 64;
  const int tid = threadIdx.x;

  const float* src = Q + ((size_t)bh * T_DIM + t0) * N_DIM + n0;
  unsigned int* qrb = qrOut + ((size_t)bh * T_DIM + t0) * 256 + (n0 >> 1);
#pragma unroll
  for (int it = 0; it < 8; ++it) {
    int pi = it * 256 + tid;           // 0..2047 pairs in 64x64 tile
    int r = pi >> 5;                   // t-local
    int c2 = pi & 31;                  // pair col
    float f = freqs[n0 + 2 * c2];
    f32x2 qv = *(const f32x2*)(src + (size_t)r * N_DIM + 2 * c2);
    float ph = (float)(t0 + r) * f;
    ph = ph - floorf(ph);              // revolutions in [0,1)
    float sn = __builtin_amdgcn_sinf(ph);
    float cn = __builtin_amdgcn_cosf(ph);
    unsigned lo = bf16rne(qv.x * cn - qv.y * sn);
    unsigned hi = bf16rne(qv.y * cn + qv.x * sn);
    qrb[(size_t)r * 256 + c2] = lo | (hi << 16);
    tile[r][2 * c2] = (unsigned short)lo;
    tile[r][2 * c2 + 1] = (unsigned short)hi;
  }
  __syncthreads();
  unsigned int* dstb = qrTOut + ((size_t)bh * N_DIM + n0) * 1024 + (t0 >> 1);
#pragma unroll
  for (int it = 0; it < 8; ++it) {
    int slot = it * 256 + tid;         // 0..2047
    int rn = slot >> 5;                // n-local 0..63
    int c2 = slot & 31;                // t-pair 0..31
    unsigned lo = tile[2 * c2][rn];
    unsigned hi = tile[2 * c2 + 1][rn];
    dstb[(size_t)rn * 1024 + c2] = lo | (hi << 16);
  }
}

// ---- V fp32 [bh][t][d] -> frag-linear bf16 blocks (16x16x32 B-frag):
// vt[bh][sblk32][slot=df*64+lane][i] = V[s0+8*(lane>>4)+i][16*df+(lane&15)]
__global__ void vtrans_kernel(const float* __restrict__ V, unsigned short* __restrict__ vt32) {
  __shared__ unsigned short tile[32][128];
  const int bid = blockIdx.x;
  const int bh = (bid & 7) + 8 * ((bid >> 3) & 1);
  const int sb = bid >> 4;             // 0..63
  const float* src = V + ((size_t)bh * T_DIM + sb * 32) * DV_DIM;
  const int tid = threadIdx.x;
#pragma unroll
  for (int i = 0; i < 16; ++i) {
    int idx = i * 256 + tid;
    tile[idx >> 7][idx & 127] = (unsigned short)bf16rne(src[idx]);
  }
  __syncthreads();
  unsigned short* dst = vt32 + ((size_t)bh * 64 + sb) * 4096;
#pragma unroll
  for (int jj = 0; jj < 2; ++jj) {
    int j = jj * 256 + tid;
    int df = j >> 6, ln = j & 63;
    int lh2 = ln & 15, lg2 = ln >> 4;
    unsigned short tmp[8];
#pragma unroll
    for (int i = 0; i < 8; ++i) tmp[i] = tile[8 * lg2 + i][16 * df + lh2];
    *(u32x4*)(dst + j * 8) = *(u32x4*)tmp;
  }
}

// ---------------- fused G + exclusive prefix -> H ----------------
// H[t] = sum_{chunks k < i} QR_k^T V_k, emitted bf16 B-frag-linear.
__global__ __launch_bounds__(256, 1)
void hprefix_kernel(const unsigned short* __restrict__ qrT,
                    const unsigned short* __restrict__ vt,
                    unsigned short* __restrict__ H) {
  const int bid = blockIdx.x;
  const int bh = (bid & 7) + 8 * ((bid >> 3) & 1);
  const int slab = bid >> 4;           // 0..15
  const int nsl = slab >> 2;
  const int dsl = slab & 3;
  const int tid = threadIdx.x;
  const int w = tid >> 6;
  const int lane = tid & 63;
  const int lh = lane & 15, lg = lane >> 4;

  const unsigned short* qrT_h = qrT + (size_t)bh * (N_DIM * T_DIM);
  const unsigned short* vt_h = vt + (size_t)bh * (64 * 4096);
  unsigned short* H_h = H + (size_t)bh * (16 * 65536);

  const f32x4 fzero = {0.f, 0.f, 0.f, 0.f};
  f32x4 acc00 = fzero, acc01 = fzero, acc10 = fzero, acc11 = fzero;

  for (int ch = 0; ch < 16; ++ch) {
    // ---- emit H_ch = prefix so far (exclusive) ----
#pragma unroll
    for (int nf = 0; nf < 2; ++nf)
#pragma unroll
      for (int dfl = 0; dfl < 2; ++dfl) {
        const f32x4 a = (nf == 0) ? (dfl == 0 ? acc00 : acc01)
                                  : (dfl == 0 ? acc10 : acc11);
        int nloc = w * 32 + nf * 16 + 4 * lg;
        int nblk = nsl * 4 + (nloc >> 5);
        int lg2 = (nloc >> 3) & 3;
        int i0 = nloc & 7;
        int df = dsl * 2 + dfl;
        int slot = df * 64 + lg2 * 16 + lh;
        u32x2 pk;
        pk[0] = bf16rne(a[0]) | (bf16rne(a[1]) << 16);
        pk[1] = bf16rne(a[2]) | (bf16rne(a[3]) << 16);
        *(u32x2*)(H_h + (size_t)ch * 65536 + nblk * 4096 + slot * 8 + i0) = pk;
      }
    // ---- accumulate G_ch ----
#pragma unroll
    for (int ks = 0; ks < 4; ++ks) {
      u32x4 a0, a1, b0, b1;
      {
        const unsigned short* pa = qrT_h + (size_t)(nsl * 128 + w * 32 + lh) * T_DIM
                                   + ch * 128 + ks * 32 + lg * 8;
        a0 = *(const u32x4*)pa;
        a1 = *(const u32x4*)(pa + 16 * T_DIM);
        const unsigned short* pb = vt_h + (size_t)(ch * 4 + ks) * 4096
                                   + ((dsl * 2) * 64 + lane) * 8;
        b0 = *(const u32x4*)pb;
        b1 = *(const u32x4*)(pb + 512);
      }
      acc00 = __builtin_amdgcn_mfma_f32_16x16x32_bf16(__builtin_bit_cast(bf16x8, a0), __builtin_bit_cast(bf16x8, b0), acc00, 0, 0, 0);
      acc01 = __builtin_amdgcn_mfma_f32_16x16x32_bf16(__builtin_bit_cast(bf16x8, a0), __builtin_bit_cast(bf16x8, b1), acc01, 0, 0, 0);
      acc10 = __builtin_amdgcn_mfma_f32_16x16x32_bf16(__builtin_bit_cast(bf16x8, a1), __builtin_bit_cast(bf16x8, b0), acc10, 0, 0, 0);
      acc11 = __builtin_amdgcn_mfma_f32_16x16x32_bf16(__builtin_bit_cast(bf16x8, a1), __builtin_bit_cast(bf16x8, b1), acc11, 0, 0, 0);
    }
  }
}

// ---------------- per-chunk output: O = QR_i H_i + tril(QR_i QR_i^T,-1) V_i ----------------
// 256 wgs = (head pinned to XCD, ch) x 512 thr (8 waves; wave w owns 16
// t-rows, ALL 8 d-frags). K staged read-once via 2x32KB LDS dbuf (counted
// vmcnt(4) + raw barriers, v10-proven); the same 64KB then serves as the H
// dbuf for 4 df-pair stages (overlay; H read-once). PV vt frags via tracked
// global reads. 96KB LDS -> 1 wg/CU; launch_bounds(512,1) -> VGPR-rich.
__global__ __launch_bounds__(512, 1)
void chunk_kernel(const unsigned short* __restrict__ qr,
                  const unsigned short* __restrict__ vt,
                  const unsigned short* __restrict__ H,
                  float* __restrict__ out) {
  __shared__ unsigned short kh_lds[2][16384];  // 2x32KB: K dbuf, then H dbuf
  __shared__ unsigned short p_lds[8 * 2048];   // 32KB: [wave][sb 4][A-frag 512]

  const int tid = threadIdx.x;
  const int w = tid >> 6;              // 0..7
  const int lane = tid & 63;
  const int lh = lane & 15, lg = lane >> 4;

  const int bid = blockIdx.x;          // 256 wgs
  const int head = (bid & 7) + 8 * ((bid >> 3) & 1);
  const int ch = bid >> 4;             // 0..15

  const unsigned short* qr_h = qr + (size_t)head * (T_DIM * N_DIM);
  const unsigned short* vt_h = vt + (size_t)head * (64 * 4096);
  const unsigned short* H_c = H + ((size_t)head * 16 + ch) * 65536;
  float* out_h = out + (size_t)head * (T_DIM * DV_DIM);

  const int tq = w * 16;               // t local to chunk
  const int tb = ch * 128 + tq;
  const int nsb = (w >> 1) + 1;        // causal 32-s blocks for this wave

  // K stage: 32-row block sb -> A-frag-linear [f=st*16+ks][lane*8], 32KB
  int koff[4];
#pragma unroll
  for (int it = 0; it < 4; ++it) {
    int j = it * 512 + tid;            // slot 0..2047
    int f = j >> 6, l = j & 63;
    int st = f >> 4, ks = f & 15;
    koff[it] = (st * 16 + (l & 15)) * 1024 + ks * 64 + (l >> 4) * 16;
  }
  auto stageK = [&](int sb, int buf) {
    const char* kb = (const char*)qr_h + ((size_t)ch * 128 + sb * 32) * 1024;
#pragma unroll
    for (int it = 0; it < 4; ++it)
      load_lds16(kb + koff[it], (char*)&kh_lds[buf][0] + (it * 512 + tid) * 16);
  };
  // H stage q (df-pair 2q,2q+1): [nb 16][dfp 2][lane][8] = 32KB
  auto stageH = [&](int q, int buf) {
#pragma unroll
    for (int it = 0; it < 4; ++it) {
      int s = it * 512 + tid;          // slot 0..2047
      int nb = s >> 7;
      int dfp = (s >> 6) & 1;
      int l = s & 63;
      const unsigned short* src = H_c + nb * 4096 + (2 * q + dfp) * 512 + l * 8;
      load_lds16(src, (char*)&kh_lds[buf][0] + s * 16);
    }
  };

  stageK(0, 0);
  stageK(1, 1);

  // ---- Q fragments (tracked loads): row = t = tb+lh, k = 32ks+8lg+i ----
  u32x4 qf[16];
  {
    const unsigned short* pq = qr_h + (size_t)(tb + lh) * N_DIM + lg * 8;
#pragma unroll
    for (int ks = 0; ks < 16; ++ks) qf[ks] = *(const u32x4*)(pq + ks * 32);
  }

  const f32x4 fzero = {0.f, 0.f, 0.f, 0.f};
  f32x4 o[8];
#pragma unroll
  for (int df = 0; df < 8; ++df) o[df] = fzero;

  // ---- QK loop: 4 staged iterations, counted vmcnt, uniform barriers ----
  for (int sb = 0; sb < 4; ++sb) {
    asm volatile("s_waitcnt vmcnt(4)" ::: "memory");  // K(sb) landed
    __builtin_amdgcn_s_barrier();
    __builtin_amdgcn_sched_barrier(0);

    if (sb < nsb) {
      f32x4 sA = fzero, sB = fzero;
      const unsigned short* kbuf = &kh_lds[sb & 1][0];
#pragma unroll
      for (int ks = 0; ks < 16; ++ks) {
        bf16x8 kf0 = *(const bf16x8*)(kbuf + ks * 512 + lane * 8);
        bf16x8 kf1 = *(const bf16x8*)(kbuf + (16 + ks) * 512 + lane * 8);
        bf16x8 qb = __builtin_bit_cast(bf16x8, qf[ks]);
        sA = __builtin_amdgcn_mfma_f32_16x16x32_bf16(kf0, qb, sA, 0, 0, 0);
        sB = __builtin_amdgcn_mfma_f32_16x16x32_bf16(kf1, qb, sB, 0, 0, 0);
      }
      const int tloc = tq + lh;
#pragma unroll
      for (int r = 0; r < 4; ++r) {
        if (sb * 32 + 4 * lg + r >= tloc) sA[r] = 0.f;
        if (sb * 32 + 16 + 4 * lg + r >= tloc) sB[r] = 0.f;
      }
      u32x2 pkA, pkB;
      pkA[0] = bf16rne(sA[0]) | (bf16rne(sA[1]) << 16);
      pkA[1] = bf16rne(sA[2]) | (bf16rne(sA[3]) << 16);
      pkB[0] = bf16rne(sB[0]) | (bf16rne(sB[1]) << 16);
      pkB[1] = bf16rne(sB[2]) | (bf16rne(sB[3]) << 16);
      const int sa_in = 4 * lg;
      const int sb_in = 16 + 4 * lg;
      *(u32x2*)&p_lds[w * 2048 + sb * 512 + ((sa_in >> 3) * 16 + lh) * 8 + (sa_in & 7)] = pkA;
      *(u32x2*)&p_lds[w * 2048 + sb * 512 + ((sb_in >> 3) * 16 + lh) * 8 + (sb_in & 7)] = pkB;
    }

    asm volatile("s_waitcnt lgkmcnt(0)" ::: "memory");
    __builtin_amdgcn_sched_barrier(0);
    __builtin_amdgcn_s_barrier();      // buf (sb&1) free for restage

    if (sb == 0) stageK(2, 0);
    else if (sb == 1) stageK(3, 1);
    else if (sb == 2) stageH(0, 0);    // hides under sb=3 + PV
  }
  stageH(1, 1);

  // ---- PV: O += P * V_i (vt frags via tracked global; L2-local) ----
  for (int f = 0; f < nsb; ++f) {
    bf16x8 pa = *(const bf16x8*)&p_lds[w * 2048 + f * 512 + lane * 8];
    const unsigned short* vb = vt_h + (size_t)(ch * 4 + f) * 4096 + lane * 8;
#pragma unroll
    for (int df = 0; df < 8; ++df) {
      bf16x8 vf = *(const bf16x8*)(vb + df * 512);
      o[df] = __builtin_amdgcn_mfma_f32_16x16x32_bf16(pa, vf, o[df], 0, 0, 0);
    }
  }

  // ---- QH loop: 4 df-pair stages from overlaid LDS dbuf (H_0 = 0 exact) ----
  for (int q = 0; q < 4; ++q) {
    if (q < 3) asm volatile("s_waitcnt vmcnt(4)" ::: "memory");
    else       asm volatile("s_waitcnt vmcnt(0)" ::: "memory");
    __builtin_amdgcn_s_barrier();
    __builtin_amdgcn_sched_barrier(0);

    const unsigned short* hbuf = &kh_lds[q & 1][0];
#pragma unroll
    for (int ks = 0; ks < 16; ++ks) {
      bf16x8 qa = __builtin_bit_cast(bf16x8, qf[ks]);
      bf16x8 hf0 = *(const bf16x8*)(hbuf + ks * 1024 + lane * 8);
      bf16x8 hf1 = *(const bf16x8*)(hbuf + ks * 1024 + 512 + lane * 8);
      o[2 * q] = __builtin_amdgcn_mfma_f32_16x16x32_bf16(qa, hf0, o[2 * q], 0, 0, 0);
      o[2 * q + 1] = __builtin_amdgcn_mfma_f32_16x16x32_bf16(qa, hf1, o[2 * q + 1], 0, 0, 0);
    }

    asm volatile("s_waitcnt lgkmcnt(0)" ::: "memory");
    __builtin_amdgcn_sched_barrier(0);
    __builtin_amdgcn_s_barrier();      // half (q&1) free for restage

    if (q < 2) stageH(q + 2, q & 1);
  }

  // ---- epilogue: plain stores, each element written exactly once ----
  float* ob = out_h + (size_t)(tb + 4 * lg) * DV_DIM + lh;
#pragma unroll
  for (int df = 0; df < 8; ++df)
#pragma unroll
    for (int r = 0; r < 4; ++r)
      ob[(size_t)r * DV_DIM + df * 16] = o[df][r];
}

extern "C" void kernel_launch(void* const* d_in, const int* in_sizes, int n_in,
                              void* d_out, int out_size, void* d_ws, size_t ws_size,
                              hipStream_t stream) {
  const float* Q = (const float*)d_in[0];
  const float* V = (const float*)d_in[1];
  const float* freqs = (const float*)d_in[2];
  float* out = (float*)d_out;

  unsigned short* qr = (unsigned short*)d_ws;                 // 33.5 MB
  unsigned short* qrT = qr + (size_t)16777216;                // 33.5 MB
  unsigned short* vt = qrT + (size_t)16777216;                // 8.4 MB
  unsigned short* H = vt + (size_t)4194304;                   // 33.5 MB

  hipLaunchKernelGGL(ropeT_kernel, dim3(4096), dim3(256), 0, stream,
                     Q, freqs, (unsigned int*)qr, (unsigned int*)qrT);
  hipLaunchKernelGGL(vtrans_kernel, dim3(NH * 64), dim3(256), 0, stream, V, vt);
  hipLaunchKernelGGL(hprefix_kernel, dim3(256), dim3(256), 0, stream, qrT, vt, H);
  hipLaunchKernelGGL(chunk_kernel, dim3(256), dim3(512), 0, stream, qr, vt, H, out);
}